// Round 1
// 229.585 us; speedup vs baseline: 1.0520x; 1.0520x over previous
//
#include <hip/hip_runtime.h>
#include <math.h>

typedef _Float16 half_t;
typedef _Float16 half8 __attribute__((ext_vector_type(8)));
typedef _Float16 half4_t __attribute__((ext_vector_type(4)));
typedef _Float16 half2_t __attribute__((ext_vector_type(2)));
typedef float floatx4 __attribute__((ext_vector_type(4)));

#define M_TOK 512
#define N_DIM 2048
#define D_HEAD 128
#define H_HEADS 16
#define L_CACHE 4096
#define THREE_N 6144
#define NCHUNK 8
#define LCHUNK 512

// ---------------------------------------------------------------------------
// Kernel 1: merged prep. Regions by blockIdx.x:
//   [0,8192)        convert cache_K fp32 -> K16 fp16 (same [H,L,D] layout)
//   [8192,9216)     convert X fp32 -> X16 fp16
//   [9216,17408)    transpose cache_V [H,L,D] fp32 -> V16T [H,D,L] fp16
//   [17408,29696)   transpose W [K,N3] fp32 -> W16T [N3,K] fp16
// ---------------------------------------------------------------------------
__global__ __launch_bounds__(256) void prep_kernel(const float* __restrict__ cK,
                                                   const float* __restrict__ cV,
                                                   const float* __restrict__ W,
                                                   const float* __restrict__ X,
                                                   half_t* __restrict__ K16,
                                                   half_t* __restrict__ V16T,
                                                   half_t* __restrict__ W16T,
                                                   half_t* __restrict__ X16) {
    __shared__ half_t tile[32 * 36];
    int b = blockIdx.x;
    int t = threadIdx.x;

    if (b < 8192) {  // convert K
        size_t i = ((size_t)b * 256 + t) * 4;
        float4 v = *(const float4*)(cK + i);
        half4_t h = {(half_t)v.x, (half_t)v.y, (half_t)v.z, (half_t)v.w};
        *(half4_t*)(K16 + i) = h;
        return;
    }
    b -= 8192;
    if (b < 1024) {  // convert X
        size_t i = ((size_t)b * 256 + t) * 4;
        float4 v = *(const float4*)(X + i);
        half4_t h = {(half_t)v.x, (half_t)v.y, (half_t)v.z, (half_t)v.w};
        *(half4_t*)(X16 + i) = h;
        return;
    }
    b -= 1024;
    if (b < 8192) {  // transpose V: 32(l) x 32(d) tiles
        int h = b >> 9;
        int rem = b & 511;
        int lt = rem >> 2, dt = rem & 3;
        int l0 = lt * 32, d0 = dt * 32;
        {
            int li = t >> 3, c4 = (t & 7) * 4;
            float4 v = *(const float4*)(cV + ((size_t)h * L_CACHE + l0 + li) * D_HEAD + d0 + c4);
            tile[li * 36 + c4 + 0] = (half_t)v.x;
            tile[li * 36 + c4 + 1] = (half_t)v.y;
            tile[li * 36 + c4 + 2] = (half_t)v.z;
            tile[li * 36 + c4 + 3] = (half_t)v.w;
        }
        __syncthreads();
        {
            int di = t >> 3, lj = (t & 7) * 4;
            half4_t o = {tile[(lj + 0) * 36 + di], tile[(lj + 1) * 36 + di],
                         tile[(lj + 2) * 36 + di], tile[(lj + 3) * 36 + di]};
            *(half4_t*)(V16T + ((size_t)h * D_HEAD + d0 + di) * L_CACHE + l0 + lj) = o;
        }
        return;
    }
    b -= 8192;
    {  // transpose W: 32(k) x 32(n) tiles, b in [0,12288)
        int n0 = (b % 192) * 32, k0 = (b / 192) * 32;
        {
            int ki = t >> 3, n4 = (t & 7) * 4;
            float4 v = *(const float4*)(W + (size_t)(k0 + ki) * THREE_N + n0 + n4);
            tile[ki * 36 + n4 + 0] = (half_t)v.x;
            tile[ki * 36 + n4 + 1] = (half_t)v.y;
            tile[ki * 36 + n4 + 2] = (half_t)v.z;
            tile[ki * 36 + n4 + 3] = (half_t)v.w;
        }
        __syncthreads();
        {
            int ni = t >> 3, k4 = (t & 7) * 4;
            half4_t o = {tile[(k4 + 0) * 36 + ni], tile[(k4 + 1) * 36 + ni],
                         tile[(k4 + 2) * 36 + ni], tile[(k4 + 3) * 36 + ni]};
            *(half4_t*)(W16T + (size_t)(n0 + ni) * N_DIM + k0 + k4) = o;
        }
    }
}

// ---------------------------------------------------------------------------
// Kernel 2: fused GEMM + RMS-norm + scatter (incl. direct V^T write).
// Tile = X16[64m x 2048] @ W16T[128n x 2048]^T. bx 0..15 q-head, 16..31
// k-head (-> K16 rows P..P+M, fp16), 32..47 v-head (-> V16T via LDS transpose).
// ---------------------------------------------------------------------------
__global__ __launch_bounds__(256) void gemm_fused_kernel(const half_t* __restrict__ X16,
                                                         const half_t* __restrict__ W16T,
                                                         const int* __restrict__ Pp,
                                                         half_t* __restrict__ Q16,
                                                         half_t* __restrict__ K16,
                                                         half_t* __restrict__ V16T) {
    __shared__ half_t As[64 * 72];   // [m][k] BK=64
    __shared__ half_t Bs[128 * 72];  // [n][k]
    __shared__ half_t Vt[128 * 72];  // epilogue transpose buffer (seg 2)
    __shared__ float ssbuf[4][32];
    const int t = threadIdx.x;
    const int wid = t >> 6, lane = t & 63;
    const int quad = lane >> 4, ln = lane & 15;
    const int bx = blockIdx.x, by = blockIdx.y;
    const int m0 = by * 64, n0 = bx * 128;
    const int wm = (wid >> 1) * 32, wn = (wid & 1) * 64;

    floatx4 acc[2][4] = {};

    const int ar = t >> 3, ag = (t & 7) * 8;  // A: 32 rows/pass, 2 passes
    const int br = t >> 3, bg = (t & 7) * 8;  // B: 32 rows/pass, 4 passes

    for (int k0 = 0; k0 < N_DIM; k0 += 64) {
        __syncthreads();
#pragma unroll
        for (int p = 0; p < 2; ++p) {
            int r = ar + p * 32;
            *(half8*)&As[r * 72 + ag] =
                *(const half8*)(X16 + (size_t)(m0 + r) * N_DIM + k0 + ag);
        }
#pragma unroll
        for (int p = 0; p < 4; ++p) {
            int r = br + p * 32;
            *(half8*)&Bs[r * 72 + bg] =
                *(const half8*)(W16T + (size_t)(n0 + r) * N_DIM + k0 + bg);
        }
        __syncthreads();
#pragma unroll
        for (int kt = 0; kt < 2; ++kt) {
            half8 a[2], b[4];
#pragma unroll
            for (int i = 0; i < 2; ++i)
                a[i] = *(half8*)&As[(wm + i * 16 + ln) * 72 + kt * 32 + quad * 8];
#pragma unroll
            for (int j = 0; j < 4; ++j)
                b[j] = *(half8*)&Bs[(wn + j * 16 + ln) * 72 + kt * 32 + quad * 8];
#pragma unroll
            for (int i = 0; i < 2; ++i)
#pragma unroll
                for (int j = 0; j < 4; ++j)
                    acc[i][j] = __builtin_amdgcn_mfma_f32_16x16x32_f16(a[i], b[j], acc[i][j], 0, 0, 0);
        }
    }

    const int seg = bx >> 4, h = bx & 15;
    const int P = *Pp;

    if (seg < 2) {  // q or k: RMS-norm then write
        float ss[2][4], scale[2][4];
#pragma unroll
        for (int i = 0; i < 2; ++i)
#pragma unroll
            for (int r = 0; r < 4; ++r) {
                float s = 0.f;
#pragma unroll
                for (int j = 0; j < 4; ++j) s += acc[i][j][r] * acc[i][j][r];
#pragma unroll
                for (int msk = 1; msk < 16; msk <<= 1) s += __shfl_xor(s, msk, 64);
                ss[i][r] = s;
            }
        if (ln == 0) {
#pragma unroll
            for (int i = 0; i < 2; ++i)
#pragma unroll
                for (int r = 0; r < 4; ++r)
                    ssbuf[wid][i * 16 + quad * 4 + r] = ss[i][r];
        }
        __syncthreads();
#pragma unroll
        for (int i = 0; i < 2; ++i)
#pragma unroll
            for (int r = 0; r < 4; ++r)
                scale[i][r] =
                    rsqrtf((ss[i][r] + ssbuf[wid ^ 1][i * 16 + quad * 4 + r]) * (1.0f / 128.0f));
#pragma unroll
        for (int i = 0; i < 2; ++i) {
            int mbase = m0 + wm + i * 16 + quad * 4;
#pragma unroll
            for (int j = 0; j < 4; ++j) {
                int col = wn + j * 16 + ln;
#pragma unroll
                for (int r = 0; r < 4; ++r) {
                    int m = mbase + r;
                    half_t val = (half_t)(acc[i][j][r] * scale[i][r]);
                    if (seg == 0)
                        Q16[((size_t)h * M_TOK + m) * D_HEAD + col] = val;
                    else
                        K16[((size_t)h * L_CACHE + P + m) * D_HEAD + col] = val;
                }
            }
        }
    } else {  // v: transpose via LDS, write V^T columns (coalesced 16B stores)
#pragma unroll
        for (int i = 0; i < 2; ++i) {
            int mbase = wm + i * 16 + quad * 4;
#pragma unroll
            for (int j = 0; j < 4; ++j) {
                int d = wn + j * 16 + ln;
#pragma unroll
                for (int r = 0; r < 4; ++r)
                    Vt[d * 72 + mbase + r] = (half_t)acc[i][j][r];
            }
        }
        __syncthreads();
#pragma unroll
        for (int p = 0; p < 4; ++p) {
            int s = p * 256 + t;
            int d = s >> 3, sg = s & 7;
            *(half8*)(V16T + ((size_t)h * D_HEAD + d) * L_CACHE + P + m0 + sg * 8) =
                *(half8*)&Vt[d * 72 + sg * 8];
        }
    }
}

// ---------------------------------------------------------------------------
// Kernel 3: flash attention partial over L-chunk of 512. grid = 512 blocks,
// decoded XCD-aware so the 4 m-blocks of one (h,c) share an XCD's L2.
// 128 m-rows per block: 4 waves x 2 strips of 16 rows.
// Swapped QK^T (mfma(K,Q) -> S^T): softmax column m is lane-local (m=ln),
// reductions are 15 in-reg ops + 2 shfl_xor instead of 64 shfls.
// T14 prefetch: next tile's global loads issued before current compute.
// ---------------------------------------------------------------------------
__global__ __launch_bounds__(256) void attn_partial_kernel(const half_t* __restrict__ Q16,
                                                           const half_t* __restrict__ K16,
                                                           const half_t* __restrict__ V16T,
                                                           half_t* __restrict__ Opart,
                                                           float* __restrict__ mstat,
                                                           float* __restrict__ lstat) {
    __shared__ half_t Ks[64 * 136];       // [l][d], pad 8
    __shared__ half_t Vs[128 * 72];       // [d][l], pad 8
    __shared__ half_t Ps[4 * 2 * 16 * 72];  // per-wave, per-strip P[m][l]
    const int t = threadIdx.x, w = t >> 6, lane = t & 63;
    const int quad = lane >> 4, ln = lane & 15;

    // XCD-aware decode (bijective over 512 = 64 slots x 8 XCDs): the 4
    // m-blocks of one (h,c) are consecutive slots on one XCD -> K/V L2 hits.
    const int bid = blockIdx.x;
    const int xcd = bid & 7, slot = bid >> 3;
    const int pair = (xcd << 4) | (slot >> 2);  // 16 (h,c) pairs per XCD
    const int h = pair & 15, c = pair >> 4, mi = slot & 3;
    const int mb = mi * 128;

    const half_t* Qh = Q16 + (size_t)h * M_TOK * D_HEAD;
    const half_t* Kh = K16 + (size_t)h * L_CACHE * D_HEAD;
    const half_t* Vh = V16T + (size_t)h * D_HEAD * L_CACHE;

    // Q fragments (B-operand of swapped mfma): col=ln -> m, k=quad*8+i -> d
    half8 qf[2][4];
#pragma unroll
    for (int s = 0; s < 2; ++s) {
        int m0 = mb + w * 32 + s * 16;
#pragma unroll
        for (int dt = 0; dt < 4; ++dt)
            qf[s][dt] = *(const half8*)(Qh + (size_t)(m0 + ln) * D_HEAD + dt * 32 + quad * 8);
    }

    floatx4 oacc[2][8] = {};
    float mrow[2] = {-INFINITY, -INFINITY};
    float lrow[2] = {0.f, 0.f};

    half_t* Pw = Ps + w * (2 * 16 * 72);

    const int l0base = c * LCHUNK;
    const int kr = t >> 4, kc = (t & 15) * 8;  // K staging: 16 rows/pass x 4
    const int vr = t >> 3, vc = (t & 7) * 8;   // V staging: 32 rows/pass x 4

    // prologue: load tile 0 into regs
    half8 kreg[4], vreg[4];
#pragma unroll
    for (int p = 0; p < 4; ++p) {
        kreg[p] = *(const half8*)(Kh + (size_t)(l0base + p * 16 + kr) * D_HEAD + kc);
        vreg[p] = *(const half8*)(Vh + (size_t)(p * 32 + vr) * L_CACHE + l0base + vc);
    }

    for (int it = 0; it < LCHUNK / 64; ++it) {
        __syncthreads();  // previous compute done reading Ks/Vs
#pragma unroll
        for (int p = 0; p < 4; ++p)
            *(half8*)&Ks[(p * 16 + kr) * 136 + kc] = kreg[p];
#pragma unroll
        for (int p = 0; p < 4; ++p)
            *(half8*)&Vs[(p * 32 + vr) * 72 + vc] = vreg[p];
        if (it + 1 < LCHUNK / 64) {  // prefetch next tile under compute
            int l1 = l0base + (it + 1) * 64;
#pragma unroll
            for (int p = 0; p < 4; ++p) {
                kreg[p] = *(const half8*)(Kh + (size_t)(l1 + p * 16 + kr) * D_HEAD + kc);
                vreg[p] = *(const half8*)(Vh + (size_t)(p * 32 + vr) * L_CACHE + l1 + vc);
            }
        }
        __syncthreads();  // Ks/Vs ready

        // QK^T swapped: sacc[s][nt][r] = S[m=ln][l = nt*16 + quad*4 + r]
        floatx4 sacc[2][4] = {};
#pragma unroll
        for (int dt = 0; dt < 4; ++dt) {
            half8 kf[4];
#pragma unroll
            for (int nt = 0; nt < 4; ++nt)
                kf[nt] = *(half8*)&Ks[(nt * 16 + ln) * 136 + dt * 32 + quad * 8];
#pragma unroll
            for (int s = 0; s < 2; ++s)
#pragma unroll
                for (int nt = 0; nt < 4; ++nt)
                    sacc[s][nt] = __builtin_amdgcn_mfma_f32_16x16x32_f16(kf[nt], qf[s][dt], sacc[s][nt], 0, 0, 0);
        }

        // online softmax per strip; column m=ln is lane-local
#pragma unroll
        for (int s = 0; s < 2; ++s) {
            float mx = sacc[s][0][0];
#pragma unroll
            for (int nt = 0; nt < 4; ++nt)
#pragma unroll
                for (int r = 0; r < 4; ++r) mx = fmaxf(mx, sacc[s][nt][r]);
            mx = fmaxf(mx, __shfl_xor(mx, 16));
            mx = fmaxf(mx, __shfl_xor(mx, 32));
            if (__ballot(mx > mrow[s])) {  // rescale only when max grows
                float mnew = fmaxf(mrow[s], mx);
                float alpha = __expf(mrow[s] - mnew);
                mrow[s] = mnew;
                lrow[s] *= alpha;
                float ar[4];
#pragma unroll
                for (int r = 0; r < 4; ++r) ar[r] = __shfl(alpha, quad * 4 + r, 16);
#pragma unroll
                for (int nt8 = 0; nt8 < 8; ++nt8)
#pragma unroll
                    for (int r = 0; r < 4; ++r) oacc[s][nt8][r] *= ar[r];
            }
            float psum = 0.f;
#pragma unroll
            for (int nt = 0; nt < 4; ++nt) {
                half4_t h4;
#pragma unroll
                for (int r = 0; r < 4; ++r) {
                    float p = __expf(sacc[s][nt][r] - mrow[s]);
                    psum += p;
                    h4[r] = (half_t)p;
                }
                *(half4_t*)&Pw[s * 1152 + ln * 72 + nt * 16 + quad * 4] = h4;
            }
            psum += __shfl_xor(psum, 16);
            psum += __shfl_xor(psum, 32);
            lrow[s] += psum;
        }

        // PV: A = P (row=ln -> m), B = V (col=ln -> d); share b across strips
#pragma unroll
        for (int kt = 0; kt < 2; ++kt) {
            half8 a0 = *(half8*)&Pw[ln * 72 + kt * 32 + quad * 8];
            half8 a1 = *(half8*)&Pw[1152 + ln * 72 + kt * 32 + quad * 8];
#pragma unroll
            for (int nt8 = 0; nt8 < 8; ++nt8) {
                half8 b = *(half8*)&Vs[(nt8 * 16 + ln) * 72 + kt * 32 + quad * 8];
                oacc[0][nt8] = __builtin_amdgcn_mfma_f32_16x16x32_f16(a0, b, oacc[0][nt8], 0, 0, 0);
                oacc[1][nt8] = __builtin_amdgcn_mfma_f32_16x16x32_f16(a1, b, oacc[1][nt8], 0, 0, 0);
            }
        }
    }

    half_t* Oc = Opart + ((size_t)(c * H_HEADS + h) * M_TOK) * D_HEAD;
    float* ms = mstat + (size_t)(c * H_HEADS + h) * M_TOK;
    float* ls = lstat + (size_t)(c * H_HEADS + h) * M_TOK;
#pragma unroll
    for (int s = 0; s < 2; ++s) {
        int m0 = mb + w * 32 + s * 16;
#pragma unroll
        for (int nt8 = 0; nt8 < 8; ++nt8) {
            int col = nt8 * 16 + ln;
#pragma unroll
            for (int r = 0; r < 4; ++r)
                Oc[(size_t)(m0 + quad * 4 + r) * D_HEAD + col] = (half_t)oacc[s][nt8][r];
        }
        if (lane < 16) {
            ms[m0 + lane] = mrow[s];
            ls[m0 + lane] = lrow[s];
        }
    }
}

// ---------------------------------------------------------------------------
// Kernel 4: combine NCHUNK fp16 partials. One wave per (h,m) row.
// ---------------------------------------------------------------------------
__global__ __launch_bounds__(256) void combine_kernel(const half_t* __restrict__ Opart,
                                                      const float* __restrict__ mstat,
                                                      const float* __restrict__ lstat,
                                                      float* __restrict__ out) {
    int gw = blockIdx.x * 4 + (threadIdx.x >> 6);
    int lane = threadIdx.x & 63;
    int h = gw >> 9, m = gw & 511;
    int d = lane * 2;

    float ms[NCHUNK];
    float mg = -INFINITY;
#pragma unroll
    for (int c = 0; c < NCHUNK; ++c) {
        ms[c] = mstat[((c * H_HEADS + h) << 9) + m];
        mg = fmaxf(mg, ms[c]);
    }
    float denom = 0.f, o0 = 0.f, o1 = 0.f;
#pragma unroll
    for (int c = 0; c < NCHUNK; ++c) {
        float e = __expf(ms[c] - mg);
        denom += lstat[((c * H_HEADS + h) << 9) + m] * e;
        const half_t* Oc = Opart + (((size_t)(c * H_HEADS + h) << 9) + m) * D_HEAD + d;
        half2_t v = *(const half2_t*)Oc;
        o0 += (float)v.x * e;
        o1 += (float)v.y * e;
    }
    float inv = 1.0f / denom;
    float* op = out + (size_t)m * N_DIM + h * D_HEAD + d;
    op[0] = o0 * inv;
    op[1] = o1 * inv;
}

// ---------------------------------------------------------------------------
extern "C" void kernel_launch(void* const* d_in, const int* in_sizes, int n_in,
                              void* d_out, int out_size, void* d_ws, size_t ws_size,
                              hipStream_t stream) {
    const float* X = (const float*)d_in[0];
    const float* W = (const float*)d_in[1];
    const float* cK = (const float*)d_in[2];
    const float* cV = (const float*)d_in[3];
    const int* Pp = (const int*)d_in[4];
    float* out = (float*)d_out;

    char* ws = (char*)d_ws;
    // workspace layout (bytes):
    //   Q16    @ 0           (2,097,152)
    //   K16    @ 2,097,152   (16,777,216)
    //   V16T   @ 18,874,368  (16,777,216)
    //   X16    @ 35,651,584  (2,097,152)
    //   W16T   @ 37,748,736  (25,165,824)  [dead after gemm_fused]
    //   Opart16@ 37,748,736  (16,777,216 = NCHUNK(8)*16*512*128*2) [overlays W16T]
    //   mstat  @ 71,303,168  (262,144 used)
    //   lstat  @ 71,827,456  (262,144 used)
    //   total 72,351,744 (unchanged footprint)
    half_t* Q16 = (half_t*)(ws + 0);
    half_t* K16 = (half_t*)(ws + 2097152);
    half_t* V16T = (half_t*)(ws + 18874368);
    half_t* X16 = (half_t*)(ws + 35651584);
    half_t* W16T = (half_t*)(ws + 37748736);
    half_t* Opart = (half_t*)(ws + 37748736);
    float* mstat = (float*)(ws + 71303168);
    float* lstat = (float*)(ws + 71827456);

    prep_kernel<<<29696, 256, 0, stream>>>(cK, cV, W, X, K16, V16T, W16T, X16);
    gemm_fused_kernel<<<dim3(48, 8), 256, 0, stream>>>(X16, W16T, Pp, Q16, K16, V16T);
    attn_partial_kernel<<<512, 256, 0, stream>>>(Q16, K16, V16T, Opart, mstat, lstat);
    combine_kernel<<<2048, 256, 0, stream>>>(Opart, mstat, lstat, out);
}

// Round 2
// 228.531 us; speedup vs baseline: 1.0568x; 1.0046x over previous
//
#include <hip/hip_runtime.h>
#include <math.h>

typedef _Float16 half_t;
typedef _Float16 half8 __attribute__((ext_vector_type(8)));
typedef _Float16 half4_t __attribute__((ext_vector_type(4)));
typedef _Float16 half2_t __attribute__((ext_vector_type(2)));
typedef float floatx4 __attribute__((ext_vector_type(4)));

#define M_TOK 512
#define N_DIM 2048
#define D_HEAD 128
#define H_HEADS 16
#define L_CACHE 4096
#define THREE_N 6144
#define NCHUNK 8
#define LCHUNK 512

// ---------------------------------------------------------------------------
// Kernel 1: merged prep. Regions by blockIdx.x:
//   [0,8192)        convert cache_K fp32 -> K16 fp16 (skip rows [P,P+M))
//   [8192,9216)     convert X fp32 -> X16 fp16
//   [9216,13312)    transpose cache_V [H,L,D] fp32 -> V16T [H,D,L] fp16,
//                   64(l)x32(d) tiles, 128B-coalesced half8 stores; skip [P,P+M)
//   [13312,19456)   transpose W [K,N3] fp32 -> W16T [N3,K] fp16, 64(k)x32(n)
// ---------------------------------------------------------------------------
__global__ __launch_bounds__(256) void prep_kernel(const float* __restrict__ cK,
                                                   const float* __restrict__ cV,
                                                   const float* __restrict__ W,
                                                   const float* __restrict__ X,
                                                   const int* __restrict__ Pp,
                                                   half_t* __restrict__ K16,
                                                   half_t* __restrict__ V16T,
                                                   half_t* __restrict__ W16T,
                                                   half_t* __restrict__ X16) {
    __shared__ half_t tile[32 * 68];  // transposed tile: [32 out-rows][64+4 pad]
    int b = blockIdx.x;
    int t = threadIdx.x;

    if (b < 8192) {  // convert K (1024 elems/block = 8 l-rows of one head)
        int l0 = (b & 511) * 8;
        const int P = *Pp;
        if (l0 >= P && l0 + 8 <= P + M_TOK) return;  // overwritten by gemm
        size_t i = ((size_t)b * 256 + t) * 4;
        float4 v = *(const float4*)(cK + i);
        half4_t h = {(half_t)v.x, (half_t)v.y, (half_t)v.z, (half_t)v.w};
        *(half4_t*)(K16 + i) = h;
        return;
    }
    b -= 8192;
    if (b < 1024) {  // convert X
        size_t i = ((size_t)b * 256 + t) * 4;
        float4 v = *(const float4*)(X + i);
        half4_t h = {(half_t)v.x, (half_t)v.y, (half_t)v.z, (half_t)v.w};
        *(half4_t*)(X16 + i) = h;
        return;
    }
    b -= 1024;
    if (b < 4096) {  // transpose V: 64(l) x 32(d) tiles, 256 tiles/head
        int h = b >> 8;
        int rem = b & 255;
        int lt = rem >> 2, dt = rem & 3;
        int l0 = lt * 64, d0 = dt * 32;
        const int P = *Pp;
        if (l0 >= P && l0 + 64 <= P + M_TOK) return;  // overwritten by gemm
#pragma unroll
        for (int p = 0; p < 2; ++p) {
            int li = p * 32 + (t >> 3), c4 = (t & 7) * 4;
            float4 v = *(const float4*)(cV + ((size_t)h * L_CACHE + l0 + li) * D_HEAD + d0 + c4);
            tile[(c4 + 0) * 68 + li] = (half_t)v.x;
            tile[(c4 + 1) * 68 + li] = (half_t)v.y;
            tile[(c4 + 2) * 68 + li] = (half_t)v.z;
            tile[(c4 + 3) * 68 + li] = (half_t)v.w;
        }
        __syncthreads();
        {
            int d = t >> 3, lg = (t & 7) * 8;
            *(half8*)(V16T + ((size_t)h * D_HEAD + d0 + d) * L_CACHE + l0 + lg) =
                *(half8*)&tile[d * 68 + lg];
        }
        return;
    }
    b -= 4096;
    {  // transpose W: 64(k) x 32(n) tiles, b in [0,6144)
        int n0 = (b % 192) * 32, k0 = (b / 192) * 64;
#pragma unroll
        for (int p = 0; p < 2; ++p) {
            int ki = p * 32 + (t >> 3), c4 = (t & 7) * 4;
            float4 v = *(const float4*)(W + (size_t)(k0 + ki) * THREE_N + n0 + c4);
            tile[(c4 + 0) * 68 + ki] = (half_t)v.x;
            tile[(c4 + 1) * 68 + ki] = (half_t)v.y;
            tile[(c4 + 2) * 68 + ki] = (half_t)v.z;
            tile[(c4 + 3) * 68 + ki] = (half_t)v.w;
        }
        __syncthreads();
        {
            int n = t >> 3, kg = (t & 7) * 8;
            *(half8*)(W16T + (size_t)(n0 + n) * N_DIM + k0 + kg) = *(half8*)&tile[n * 68 + kg];
        }
    }
}

// ---------------------------------------------------------------------------
// Kernel 2: fused GEMM + RMS-norm + scatter (incl. direct V^T write).
// Tile = X16[64m x 2048] @ W16T[128n x 2048]^T. bx 0..15 q-head, 16..31
// k-head (-> K16 rows P..P+M, fp16), 32..47 v-head (-> V16T via LDS transpose).
// ---------------------------------------------------------------------------
__global__ __launch_bounds__(256) void gemm_fused_kernel(const half_t* __restrict__ X16,
                                                         const half_t* __restrict__ W16T,
                                                         const int* __restrict__ Pp,
                                                         half_t* __restrict__ Q16,
                                                         half_t* __restrict__ K16,
                                                         half_t* __restrict__ V16T) {
    __shared__ half_t As[64 * 72];   // [m][k] BK=64
    __shared__ half_t Bs[128 * 72];  // [n][k]
    __shared__ half_t Vt[128 * 72];  // epilogue transpose buffer (seg 2)
    __shared__ float ssbuf[4][32];
    const int t = threadIdx.x;
    const int wid = t >> 6, lane = t & 63;
    const int quad = lane >> 4, ln = lane & 15;
    const int bx = blockIdx.x, by = blockIdx.y;
    const int m0 = by * 64, n0 = bx * 128;
    const int wm = (wid >> 1) * 32, wn = (wid & 1) * 64;

    floatx4 acc[2][4] = {};

    const int ar = t >> 3, ag = (t & 7) * 8;  // A: 32 rows/pass, 2 passes
    const int br = t >> 3, bg = (t & 7) * 8;  // B: 32 rows/pass, 4 passes

    for (int k0 = 0; k0 < N_DIM; k0 += 64) {
        __syncthreads();
#pragma unroll
        for (int p = 0; p < 2; ++p) {
            int r = ar + p * 32;
            *(half8*)&As[r * 72 + ag] =
                *(const half8*)(X16 + (size_t)(m0 + r) * N_DIM + k0 + ag);
        }
#pragma unroll
        for (int p = 0; p < 4; ++p) {
            int r = br + p * 32;
            *(half8*)&Bs[r * 72 + bg] =
                *(const half8*)(W16T + (size_t)(n0 + r) * N_DIM + k0 + bg);
        }
        __syncthreads();
#pragma unroll
        for (int kt = 0; kt < 2; ++kt) {
            half8 a[2], b[4];
#pragma unroll
            for (int i = 0; i < 2; ++i)
                a[i] = *(half8*)&As[(wm + i * 16 + ln) * 72 + kt * 32 + quad * 8];
#pragma unroll
            for (int j = 0; j < 4; ++j)
                b[j] = *(half8*)&Bs[(wn + j * 16 + ln) * 72 + kt * 32 + quad * 8];
#pragma unroll
            for (int i = 0; i < 2; ++i)
#pragma unroll
                for (int j = 0; j < 4; ++j)
                    acc[i][j] = __builtin_amdgcn_mfma_f32_16x16x32_f16(a[i], b[j], acc[i][j], 0, 0, 0);
        }
    }

    const int seg = bx >> 4, h = bx & 15;
    const int P = *Pp;

    if (seg < 2) {  // q or k: RMS-norm then write
        float ss[2][4], scale[2][4];
#pragma unroll
        for (int i = 0; i < 2; ++i)
#pragma unroll
            for (int r = 0; r < 4; ++r) {
                float s = 0.f;
#pragma unroll
                for (int j = 0; j < 4; ++j) s += acc[i][j][r] * acc[i][j][r];
#pragma unroll
                for (int msk = 1; msk < 16; msk <<= 1) s += __shfl_xor(s, msk, 64);
                ss[i][r] = s;
            }
        if (ln == 0) {
#pragma unroll
            for (int i = 0; i < 2; ++i)
#pragma unroll
                for (int r = 0; r < 4; ++r)
                    ssbuf[wid][i * 16 + quad * 4 + r] = ss[i][r];
        }
        __syncthreads();
#pragma unroll
        for (int i = 0; i < 2; ++i)
#pragma unroll
            for (int r = 0; r < 4; ++r)
                scale[i][r] =
                    rsqrtf((ss[i][r] + ssbuf[wid ^ 1][i * 16 + quad * 4 + r]) * (1.0f / 128.0f));
#pragma unroll
        for (int i = 0; i < 2; ++i) {
            int mbase = m0 + wm + i * 16 + quad * 4;
#pragma unroll
            for (int j = 0; j < 4; ++j) {
                int col = wn + j * 16 + ln;
#pragma unroll
                for (int r = 0; r < 4; ++r) {
                    int m = mbase + r;
                    half_t val = (half_t)(acc[i][j][r] * scale[i][r]);
                    if (seg == 0)
                        Q16[((size_t)h * M_TOK + m) * D_HEAD + col] = val;
                    else
                        K16[((size_t)h * L_CACHE + P + m) * D_HEAD + col] = val;
                }
            }
        }
    } else {  // v: transpose via LDS, write V^T columns (coalesced 16B stores)
#pragma unroll
        for (int i = 0; i < 2; ++i) {
            int mbase = wm + i * 16 + quad * 4;
#pragma unroll
            for (int j = 0; j < 4; ++j) {
                int d = wn + j * 16 + ln;
#pragma unroll
                for (int r = 0; r < 4; ++r)
                    Vt[d * 72 + mbase + r] = (half_t)acc[i][j][r];
            }
        }
        __syncthreads();
#pragma unroll
        for (int p = 0; p < 4; ++p) {
            int s = p * 256 + t;
            int d = s >> 3, sg = s & 7;
            *(half8*)(V16T + ((size_t)h * D_HEAD + d) * L_CACHE + P + m0 + sg * 8) =
                *(half8*)&Vt[d * 72 + sg * 8];
        }
    }
}

// ---------------------------------------------------------------------------
// Kernel 3: flash attention partial over L-chunk of 512. grid = 512 blocks,
// decoded XCD-aware so the 4 m-blocks of one (h,c) share an XCD's L2.
// 128 m-rows per block: 4 waves x 2 strips of 16 rows.
// Swapped QK^T (mfma(K,Q) -> S^T): softmax column m is lane-local (m=ln),
// reductions are 15 in-reg ops + 2 shfl_xor instead of 64 shfls.
// T14 prefetch: next tile's global loads issued before current compute.
// ---------------------------------------------------------------------------
__global__ __launch_bounds__(256) void attn_partial_kernel(const half_t* __restrict__ Q16,
                                                           const half_t* __restrict__ K16,
                                                           const half_t* __restrict__ V16T,
                                                           half_t* __restrict__ Opart,
                                                           float* __restrict__ mstat,
                                                           float* __restrict__ lstat) {
    __shared__ half_t Ks[64 * 136];       // [l][d], pad 8
    __shared__ half_t Vs[128 * 72];       // [d][l], pad 8
    __shared__ half_t Ps[4 * 2 * 16 * 72];  // per-wave, per-strip P[m][l]
    const int t = threadIdx.x, w = t >> 6, lane = t & 63;
    const int quad = lane >> 4, ln = lane & 15;

    // XCD-aware decode (bijective over 512 = 64 slots x 8 XCDs): the 4
    // m-blocks of one (h,c) are consecutive slots on one XCD -> K/V L2 hits.
    const int bid = blockIdx.x;
    const int xcd = bid & 7, slot = bid >> 3;
    const int pair = (xcd << 4) | (slot >> 2);  // 16 (h,c) pairs per XCD
    const int h = pair & 15, c = pair >> 4, mi = slot & 3;
    const int mb = mi * 128;

    const half_t* Qh = Q16 + (size_t)h * M_TOK * D_HEAD;
    const half_t* Kh = K16 + (size_t)h * L_CACHE * D_HEAD;
    const half_t* Vh = V16T + (size_t)h * D_HEAD * L_CACHE;

    // Q fragments (B-operand of swapped mfma): col=ln -> m, k=quad*8+i -> d
    half8 qf[2][4];
#pragma unroll
    for (int s = 0; s < 2; ++s) {
        int m0 = mb + w * 32 + s * 16;
#pragma unroll
        for (int dt = 0; dt < 4; ++dt)
            qf[s][dt] = *(const half8*)(Qh + (size_t)(m0 + ln) * D_HEAD + dt * 32 + quad * 8);
    }

    floatx4 oacc[2][8] = {};
    float mrow[2] = {-INFINITY, -INFINITY};
    float lrow[2] = {0.f, 0.f};

    half_t* Pw = Ps + w * (2 * 16 * 72);

    const int l0base = c * LCHUNK;
    const int kr = t >> 4, kc = (t & 15) * 8;  // K staging: 16 rows/pass x 4
    const int vr = t >> 3, vc = (t & 7) * 8;   // V staging: 32 rows/pass x 4

    // prologue: load tile 0 into regs
    half8 kreg[4], vreg[4];
#pragma unroll
    for (int p = 0; p < 4; ++p) {
        kreg[p] = *(const half8*)(Kh + (size_t)(l0base + p * 16 + kr) * D_HEAD + kc);
        vreg[p] = *(const half8*)(Vh + (size_t)(p * 32 + vr) * L_CACHE + l0base + vc);
    }

    for (int it = 0; it < LCHUNK / 64; ++it) {
        __syncthreads();  // previous compute done reading Ks/Vs
#pragma unroll
        for (int p = 0; p < 4; ++p)
            *(half8*)&Ks[(p * 16 + kr) * 136 + kc] = kreg[p];
#pragma unroll
        for (int p = 0; p < 4; ++p)
            *(half8*)&Vs[(p * 32 + vr) * 72 + vc] = vreg[p];
        if (it + 1 < LCHUNK / 64) {  // prefetch next tile under compute
            int l1 = l0base + (it + 1) * 64;
#pragma unroll
            for (int p = 0; p < 4; ++p) {
                kreg[p] = *(const half8*)(Kh + (size_t)(l1 + p * 16 + kr) * D_HEAD + kc);
                vreg[p] = *(const half8*)(Vh + (size_t)(p * 32 + vr) * L_CACHE + l1 + vc);
            }
        }
        __syncthreads();  // Ks/Vs ready

        // QK^T swapped: sacc[s][nt][r] = S[m=ln][l = nt*16 + quad*4 + r]
        floatx4 sacc[2][4] = {};
#pragma unroll
        for (int dt = 0; dt < 4; ++dt) {
            half8 kf[4];
#pragma unroll
            for (int nt = 0; nt < 4; ++nt)
                kf[nt] = *(half8*)&Ks[(nt * 16 + ln) * 136 + dt * 32 + quad * 8];
#pragma unroll
            for (int s = 0; s < 2; ++s)
#pragma unroll
                for (int nt = 0; nt < 4; ++nt)
                    sacc[s][nt] = __builtin_amdgcn_mfma_f32_16x16x32_f16(kf[nt], qf[s][dt], sacc[s][nt], 0, 0, 0);
        }

        // online softmax per strip; column m=ln is lane-local
#pragma unroll
        for (int s = 0; s < 2; ++s) {
            float mx = sacc[s][0][0];
#pragma unroll
            for (int nt = 0; nt < 4; ++nt)
#pragma unroll
                for (int r = 0; r < 4; ++r) mx = fmaxf(mx, sacc[s][nt][r]);
            mx = fmaxf(mx, __shfl_xor(mx, 16));
            mx = fmaxf(mx, __shfl_xor(mx, 32));
            if (__ballot(mx > mrow[s])) {  // rescale only when max grows
                float mnew = fmaxf(mrow[s], mx);
                float alpha = __expf(mrow[s] - mnew);
                mrow[s] = mnew;
                lrow[s] *= alpha;
                float ar[4];
#pragma unroll
                for (int r = 0; r < 4; ++r) ar[r] = __shfl(alpha, quad * 4 + r, 16);
#pragma unroll
                for (int nt8 = 0; nt8 < 8; ++nt8)
#pragma unroll
                    for (int r = 0; r < 4; ++r) oacc[s][nt8][r] *= ar[r];
            }
            float psum = 0.f;
#pragma unroll
            for (int nt = 0; nt < 4; ++nt) {
                half4_t h4;
#pragma unroll
                for (int r = 0; r < 4; ++r) {
                    float p = __expf(sacc[s][nt][r] - mrow[s]);
                    psum += p;
                    h4[r] = (half_t)p;
                }
                *(half4_t*)&Pw[s * 1152 + ln * 72 + nt * 16 + quad * 4] = h4;
            }
            psum += __shfl_xor(psum, 16);
            psum += __shfl_xor(psum, 32);
            lrow[s] += psum;
        }

        // PV: A = P (row=ln -> m), B = V (col=ln -> d); share b across strips
#pragma unroll
        for (int kt = 0; kt < 2; ++kt) {
            half8 a0 = *(half8*)&Pw[ln * 72 + kt * 32 + quad * 8];
            half8 a1 = *(half8*)&Pw[1152 + ln * 72 + kt * 32 + quad * 8];
#pragma unroll
            for (int nt8 = 0; nt8 < 8; ++nt8) {
                half8 b = *(half8*)&Vs[(nt8 * 16 + ln) * 72 + kt * 32 + quad * 8];
                oacc[0][nt8] = __builtin_amdgcn_mfma_f32_16x16x32_f16(a0, b, oacc[0][nt8], 0, 0, 0);
                oacc[1][nt8] = __builtin_amdgcn_mfma_f32_16x16x32_f16(a1, b, oacc[1][nt8], 0, 0, 0);
            }
        }
    }

    half_t* Oc = Opart + ((size_t)(c * H_HEADS + h) * M_TOK) * D_HEAD;
    float* ms = mstat + (size_t)(c * H_HEADS + h) * M_TOK;
    float* ls = lstat + (size_t)(c * H_HEADS + h) * M_TOK;
#pragma unroll
    for (int s = 0; s < 2; ++s) {
        int m0 = mb + w * 32 + s * 16;
#pragma unroll
        for (int nt8 = 0; nt8 < 8; ++nt8) {
            int col = nt8 * 16 + ln;
#pragma unroll
            for (int r = 0; r < 4; ++r)
                Oc[(size_t)(m0 + quad * 4 + r) * D_HEAD + col] = (half_t)oacc[s][nt8][r];
        }
        if (lane < 16) {
            ms[m0 + lane] = mrow[s];
            ls[m0 + lane] = lrow[s];
        }
    }
}

// ---------------------------------------------------------------------------
// Kernel 4: combine NCHUNK fp16 partials. One wave per (h,m) row.
// ---------------------------------------------------------------------------
__global__ __launch_bounds__(256) void combine_kernel(const half_t* __restrict__ Opart,
                                                      const float* __restrict__ mstat,
                                                      const float* __restrict__ lstat,
                                                      float* __restrict__ out) {
    int gw = blockIdx.x * 4 + (threadIdx.x >> 6);
    int lane = threadIdx.x & 63;
    int h = gw >> 9, m = gw & 511;
    int d = lane * 2;

    float ms[NCHUNK];
    float mg = -INFINITY;
#pragma unroll
    for (int c = 0; c < NCHUNK; ++c) {
        ms[c] = mstat[((c * H_HEADS + h) << 9) + m];
        mg = fmaxf(mg, ms[c]);
    }
    float denom = 0.f, o0 = 0.f, o1 = 0.f;
#pragma unroll
    for (int c = 0; c < NCHUNK; ++c) {
        float e = __expf(ms[c] - mg);
        denom += lstat[((c * H_HEADS + h) << 9) + m] * e;
        const half_t* Oc = Opart + (((size_t)(c * H_HEADS + h) << 9) + m) * D_HEAD + d;
        half2_t v = *(const half2_t*)Oc;
        o0 += (float)v.x * e;
        o1 += (float)v.y * e;
    }
    float inv = 1.0f / denom;
    float* op = out + (size_t)m * N_DIM + h * D_HEAD + d;
    op[0] = o0 * inv;
    op[1] = o1 * inv;
}

// ---------------------------------------------------------------------------
extern "C" void kernel_launch(void* const* d_in, const int* in_sizes, int n_in,
                              void* d_out, int out_size, void* d_ws, size_t ws_size,
                              hipStream_t stream) {
    const float* X = (const float*)d_in[0];
    const float* W = (const float*)d_in[1];
    const float* cK = (const float*)d_in[2];
    const float* cV = (const float*)d_in[3];
    const int* Pp = (const int*)d_in[4];
    float* out = (float*)d_out;

    char* ws = (char*)d_ws;
    // workspace layout (bytes):
    //   Q16    @ 0           (2,097,152)
    //   K16    @ 2,097,152   (16,777,216)
    //   V16T   @ 18,874,368  (16,777,216)
    //   X16    @ 35,651,584  (2,097,152)
    //   W16T   @ 37,748,736  (25,165,824)  [dead after gemm_fused]
    //   Opart16@ 37,748,736  (16,777,216 = NCHUNK(8)*16*512*128*2) [overlays W16T]
    //   mstat  @ 71,303,168  (262,144 used)
    //   lstat  @ 71,827,456  (262,144 used)
    //   total 72,351,744 (unchanged footprint)
    half_t* Q16 = (half_t*)(ws + 0);
    half_t* K16 = (half_t*)(ws + 2097152);
    half_t* V16T = (half_t*)(ws + 18874368);
    half_t* X16 = (half_t*)(ws + 35651584);
    half_t* W16T = (half_t*)(ws + 37748736);
    half_t* Opart = (half_t*)(ws + 37748736);
    float* mstat = (float*)(ws + 71303168);
    float* lstat = (float*)(ws + 71827456);

    prep_kernel<<<19456, 256, 0, stream>>>(cK, cV, W, X, Pp, K16, V16T, W16T, X16);
    gemm_fused_kernel<<<dim3(48, 8), 256, 0, stream>>>(X16, W16T, Pp, Q16, K16, V16T);
    attn_partial_kernel<<<512, 256, 0, stream>>>(Q16, K16, V16T, Opart, mstat, lstat);
    combine_kernel<<<2048, 256, 0, stream>>>(Opart, mstat, lstat, out);
}

// Round 3
// 222.055 us; speedup vs baseline: 1.0877x; 1.0292x over previous
//
#include <hip/hip_runtime.h>
#include <math.h>

typedef _Float16 half_t;
typedef _Float16 half8 __attribute__((ext_vector_type(8)));
typedef _Float16 half4_t __attribute__((ext_vector_type(4)));
typedef _Float16 half2_t __attribute__((ext_vector_type(2)));
typedef float floatx4 __attribute__((ext_vector_type(4)));

#define M_TOK 512
#define N_DIM 2048
#define D_HEAD 128
#define H_HEADS 16
#define L_CACHE 4096
#define THREE_N 6144
#define NCHUNK 8
#define LCHUNK 512

// ---------------------------------------------------------------------------
// Kernel 1: merged prep, deepened memory pipelines. Regions by blockIdx.x:
//   [0,4096)      convert cache_K fp32 -> K16 fp16, 2048 elem/block (2 float4
//                 loads/thread, independent); skip rows [P,P+M)
//   [4096,4608)   convert X fp32 -> X16, 2048 elem/block
//   [4608,6656)   transpose cache_V [H,L,D] -> V16T [H,D,L] fp16, 64x64 tiles
//                 (4 indep float4 loads + 2 half8 stores/thread); skip [P,P+M)
//   [6656,9728)   transpose W [K,N3] -> W16T [N3,K] fp16, 64x64 tiles
// ---------------------------------------------------------------------------
__global__ __launch_bounds__(256) void prep_kernel(const float* __restrict__ cK,
                                                   const float* __restrict__ cV,
                                                   const float* __restrict__ W,
                                                   const float* __restrict__ X,
                                                   const int* __restrict__ Pp,
                                                   half_t* __restrict__ K16,
                                                   half_t* __restrict__ V16T,
                                                   half_t* __restrict__ W16T,
                                                   half_t* __restrict__ X16) {
    __shared__ half_t tile[64 * 66];  // transposed tile: [64 out-rows][64+2 pad]
    int b = blockIdx.x;
    int t = threadIdx.x;

    if (b < 4096) {  // convert K: 2048 elems = 16 l-rows of one head
        int l0 = (b & 255) * 16;
        const int P = *Pp;
        if (l0 >= P && l0 + 16 <= P + M_TOK) return;  // overwritten by gemm
        size_t i = (size_t)b * 2048 + t * 4;
        float4 v0 = *(const float4*)(cK + i);
        float4 v1 = *(const float4*)(cK + i + 1024);
        half4_t h0 = {(half_t)v0.x, (half_t)v0.y, (half_t)v0.z, (half_t)v0.w};
        half4_t h1 = {(half_t)v1.x, (half_t)v1.y, (half_t)v1.z, (half_t)v1.w};
        *(half4_t*)(K16 + i) = h0;
        *(half4_t*)(K16 + i + 1024) = h1;
        return;
    }
    b -= 4096;
    if (b < 512) {  // convert X
        size_t i = (size_t)b * 2048 + t * 4;
        float4 v0 = *(const float4*)(X + i);
        float4 v1 = *(const float4*)(X + i + 1024);
        half4_t h0 = {(half_t)v0.x, (half_t)v0.y, (half_t)v0.z, (half_t)v0.w};
        half4_t h1 = {(half_t)v1.x, (half_t)v1.y, (half_t)v1.z, (half_t)v1.w};
        *(half4_t*)(X16 + i) = h0;
        *(half4_t*)(X16 + i + 1024) = h1;
        return;
    }
    b -= 512;
    if (b < 2048) {  // transpose V: 64(l) x 64(d) tiles, 128 tiles/head
        int h = b >> 7;
        int rem = b & 127;
        int lt = rem >> 1, dt = rem & 1;
        int l0 = lt * 64, d0 = dt * 64;
        const int P = *Pp;
        if (l0 >= P && l0 + 64 <= P + M_TOK) return;  // overwritten by gemm
        {
            int l = t >> 2, c0 = (t & 3) * 16;
            const float* src = cV + ((size_t)h * L_CACHE + l0 + l) * D_HEAD + d0 + c0;
            float4 v[4];
#pragma unroll
            for (int j = 0; j < 4; ++j) v[j] = *(const float4*)(src + j * 4);
#pragma unroll
            for (int j = 0; j < 4; ++j) {
                tile[(c0 + j * 4 + 0) * 66 + l] = (half_t)v[j].x;
                tile[(c0 + j * 4 + 1) * 66 + l] = (half_t)v[j].y;
                tile[(c0 + j * 4 + 2) * 66 + l] = (half_t)v[j].z;
                tile[(c0 + j * 4 + 3) * 66 + l] = (half_t)v[j].w;
            }
        }
        __syncthreads();
        {
            int d = t >> 2, lg = (t & 3) * 16;
            half_t* dst = V16T + ((size_t)h * D_HEAD + d0 + d) * L_CACHE + l0 + lg;
            *(half8*)(dst) = *(half8*)&tile[d * 66 + lg];
            *(half8*)(dst + 8) = *(half8*)&tile[d * 66 + lg + 8];
        }
        return;
    }
    b -= 2048;
    {  // transpose W: 64(k) x 64(n) tiles, b in [0,3072)
        int n0 = (b % 96) * 64, k0 = (b / 96) * 64;
        {
            int k = t >> 2, c0 = (t & 3) * 16;
            const float* src = W + (size_t)(k0 + k) * THREE_N + n0 + c0;
            float4 v[4];
#pragma unroll
            for (int j = 0; j < 4; ++j) v[j] = *(const float4*)(src + j * 4);
#pragma unroll
            for (int j = 0; j < 4; ++j) {
                tile[(c0 + j * 4 + 0) * 66 + k] = (half_t)v[j].x;
                tile[(c0 + j * 4 + 1) * 66 + k] = (half_t)v[j].y;
                tile[(c0 + j * 4 + 2) * 66 + k] = (half_t)v[j].z;
                tile[(c0 + j * 4 + 3) * 66 + k] = (half_t)v[j].w;
            }
        }
        __syncthreads();
        {
            int n = t >> 2, kg = (t & 3) * 16;
            half_t* dst = W16T + (size_t)(n0 + n) * N_DIM + k0 + kg;
            *(half8*)(dst) = *(half8*)&tile[n * 66 + kg];
            *(half8*)(dst + 8) = *(half8*)&tile[n * 66 + kg + 8];
        }
    }
}

// ---------------------------------------------------------------------------
// Kernel 2: fused GEMM + RMS-norm + scatter (incl. direct V^T write).
// Tile = X16[64m x 2048] @ W16T[128n x 2048]^T. bx 0..15 q-head, 16..31
// k-head (-> K16 rows P..P+M, fp16), 32..47 v-head (-> V16T via LDS transpose).
// ---------------------------------------------------------------------------
__global__ __launch_bounds__(256) void gemm_fused_kernel(const half_t* __restrict__ X16,
                                                         const half_t* __restrict__ W16T,
                                                         const int* __restrict__ Pp,
                                                         half_t* __restrict__ Q16,
                                                         half_t* __restrict__ K16,
                                                         half_t* __restrict__ V16T) {
    __shared__ half_t As[64 * 72];   // [m][k] BK=64
    __shared__ half_t Bs[128 * 72];  // [n][k]
    __shared__ half_t Vt[128 * 72];  // epilogue transpose buffer (seg 2)
    __shared__ float ssbuf[4][32];
    const int t = threadIdx.x;
    const int wid = t >> 6, lane = t & 63;
    const int quad = lane >> 4, ln = lane & 15;
    const int bx = blockIdx.x, by = blockIdx.y;
    const int m0 = by * 64, n0 = bx * 128;
    const int wm = (wid >> 1) * 32, wn = (wid & 1) * 64;

    floatx4 acc[2][4] = {};

    const int ar = t >> 3, ag = (t & 7) * 8;  // A: 32 rows/pass, 2 passes
    const int br = t >> 3, bg = (t & 7) * 8;  // B: 32 rows/pass, 4 passes

    for (int k0 = 0; k0 < N_DIM; k0 += 64) {
        __syncthreads();
#pragma unroll
        for (int p = 0; p < 2; ++p) {
            int r = ar + p * 32;
            *(half8*)&As[r * 72 + ag] =
                *(const half8*)(X16 + (size_t)(m0 + r) * N_DIM + k0 + ag);
        }
#pragma unroll
        for (int p = 0; p < 4; ++p) {
            int r = br + p * 32;
            *(half8*)&Bs[r * 72 + bg] =
                *(const half8*)(W16T + (size_t)(n0 + r) * N_DIM + k0 + bg);
        }
        __syncthreads();
#pragma unroll
        for (int kt = 0; kt < 2; ++kt) {
            half8 a[2], b[4];
#pragma unroll
            for (int i = 0; i < 2; ++i)
                a[i] = *(half8*)&As[(wm + i * 16 + ln) * 72 + kt * 32 + quad * 8];
#pragma unroll
            for (int j = 0; j < 4; ++j)
                b[j] = *(half8*)&Bs[(wn + j * 16 + ln) * 72 + kt * 32 + quad * 8];
#pragma unroll
            for (int i = 0; i < 2; ++i)
#pragma unroll
                for (int j = 0; j < 4; ++j)
                    acc[i][j] = __builtin_amdgcn_mfma_f32_16x16x32_f16(a[i], b[j], acc[i][j], 0, 0, 0);
        }
    }

    const int seg = bx >> 4, h = bx & 15;
    const int P = *Pp;

    if (seg < 2) {  // q or k: RMS-norm then write
        float ss[2][4], scale[2][4];
#pragma unroll
        for (int i = 0; i < 2; ++i)
#pragma unroll
            for (int r = 0; r < 4; ++r) {
                float s = 0.f;
#pragma unroll
                for (int j = 0; j < 4; ++j) s += acc[i][j][r] * acc[i][j][r];
#pragma unroll
                for (int msk = 1; msk < 16; msk <<= 1) s += __shfl_xor(s, msk, 64);
                ss[i][r] = s;
            }
        if (ln == 0) {
#pragma unroll
            for (int i = 0; i < 2; ++i)
#pragma unroll
                for (int r = 0; r < 4; ++r)
                    ssbuf[wid][i * 16 + quad * 4 + r] = ss[i][r];
        }
        __syncthreads();
#pragma unroll
        for (int i = 0; i < 2; ++i)
#pragma unroll
            for (int r = 0; r < 4; ++r)
                scale[i][r] =
                    rsqrtf((ss[i][r] + ssbuf[wid ^ 1][i * 16 + quad * 4 + r]) * (1.0f / 128.0f));
#pragma unroll
        for (int i = 0; i < 2; ++i) {
            int mbase = m0 + wm + i * 16 + quad * 4;
#pragma unroll
            for (int j = 0; j < 4; ++j) {
                int col = wn + j * 16 + ln;
#pragma unroll
                for (int r = 0; r < 4; ++r) {
                    int m = mbase + r;
                    half_t val = (half_t)(acc[i][j][r] * scale[i][r]);
                    if (seg == 0)
                        Q16[((size_t)h * M_TOK + m) * D_HEAD + col] = val;
                    else
                        K16[((size_t)h * L_CACHE + P + m) * D_HEAD + col] = val;
                }
            }
        }
    } else {  // v: transpose via LDS, write V^T columns (coalesced 16B stores)
#pragma unroll
        for (int i = 0; i < 2; ++i) {
            int mbase = wm + i * 16 + quad * 4;
#pragma unroll
            for (int j = 0; j < 4; ++j) {
                int d = wn + j * 16 + ln;
#pragma unroll
                for (int r = 0; r < 4; ++r)
                    Vt[d * 72 + mbase + r] = (half_t)acc[i][j][r];
            }
        }
        __syncthreads();
#pragma unroll
        for (int p = 0; p < 4; ++p) {
            int s = p * 256 + t;
            int d = s >> 3, sg = s & 7;
            *(half8*)(V16T + ((size_t)h * D_HEAD + d) * L_CACHE + P + m0 + sg * 8) =
                *(half8*)&Vt[d * 72 + sg * 8];
        }
    }
}

// ---------------------------------------------------------------------------
// Kernel 3: flash attention partial over L-chunk of 512. grid = 1024 blocks
// (8 m-blocks x 16 h x 8 c), all co-resident (4 blocks/CU, 40KB LDS).
// 64 m-rows per block: 4 waves x 1 strip of 16 rows. Swapped QK^T, XOR-
// swizzled LDS (T2: col ^= (row&7)<<3, power-of-2 pitches) for conflict-free
// ds_read_b128. XCD decode: chunk c -> XCD c, K/V working set = 4MB = L2.
// ---------------------------------------------------------------------------
__global__ __launch_bounds__(256, 4) void attn_partial_kernel(const half_t* __restrict__ Q16,
                                                              const half_t* __restrict__ K16,
                                                              const half_t* __restrict__ V16T,
                                                              half_t* __restrict__ Opart,
                                                              float* __restrict__ mstat,
                                                              float* __restrict__ lstat) {
    __shared__ half_t Ks[64 * 128];      // [l][d], swizzled
    __shared__ half_t Vs[128 * 64];      // [d][l], swizzled
    __shared__ half_t Ps[4 * 16 * 64];   // per-wave P[m][l], swizzled
    const int t = threadIdx.x, w = t >> 6, lane = t & 63;
    const int quad = lane >> 4, ln = lane & 15;

    // bijective XCD decode over 1024 = 128 slots x 8 XCDs
    const int bid = blockIdx.x;
    const int xcd = bid & 7, slot = bid >> 3;
    const int pair = (xcd << 4) | (slot >> 3);  // 16 (h,c) pairs per XCD
    const int h = pair & 15, c = pair >> 4, mi = slot & 7;
    const int mb = mi * 64;

    const half_t* Qh = Q16 + (size_t)h * M_TOK * D_HEAD;
    const half_t* Kh = K16 + (size_t)h * L_CACHE * D_HEAD;
    const half_t* Vh = V16T + (size_t)h * D_HEAD * L_CACHE;

    // Q fragments (B-operand of swapped mfma): col=ln -> m, k=quad*8+i -> d
    const int m0 = mb + w * 16;
    half8 qf[4];
#pragma unroll
    for (int dt = 0; dt < 4; ++dt)
        qf[dt] = *(const half8*)(Qh + (size_t)(m0 + ln) * D_HEAD + dt * 32 + quad * 8);

    floatx4 oacc[8] = {};
    float mrow = -INFINITY;
    float lrow = 0.f;

    half_t* Pw = Ps + w * (16 * 64);
    const int psw = (ln & 7) << 3;  // P swizzle key (row = ln)

    const int l0base = c * LCHUNK;
    const int kr = t >> 4, kc = (t & 15) * 8;  // K staging: 16 rows/pass x 4
    const int vr = t >> 3, vc = (t & 7) * 8;   // V staging: 32 rows/pass x 4
    const int ksw = (kr & 7) << 3;             // K stage swizzle (row&7 = kr&7)
    const int vsw = (vr & 7) << 3;             // V stage swizzle (row&7 = vr&7)

    // prologue: load tile 0 into regs
    half8 kreg[4], vreg[4];
#pragma unroll
    for (int p = 0; p < 4; ++p) {
        kreg[p] = *(const half8*)(Kh + (size_t)(l0base + p * 16 + kr) * D_HEAD + kc);
        vreg[p] = *(const half8*)(Vh + (size_t)(p * 32 + vr) * L_CACHE + l0base + vc);
    }

    for (int it = 0; it < LCHUNK / 64; ++it) {
        __syncthreads();  // previous compute done reading Ks/Vs
#pragma unroll
        for (int p = 0; p < 4; ++p)
            *(half8*)&Ks[(p * 16 + kr) * 128 + (kc ^ ksw)] = kreg[p];
#pragma unroll
        for (int p = 0; p < 4; ++p)
            *(half8*)&Vs[(p * 32 + vr) * 64 + (vc ^ vsw)] = vreg[p];
        if (it + 1 < LCHUNK / 64) {  // prefetch next tile under compute
            int l1 = l0base + (it + 1) * 64;
#pragma unroll
            for (int p = 0; p < 4; ++p) {
                kreg[p] = *(const half8*)(Kh + (size_t)(l1 + p * 16 + kr) * D_HEAD + kc);
                vreg[p] = *(const half8*)(Vh + (size_t)(p * 32 + vr) * L_CACHE + l1 + vc);
            }
        }
        __syncthreads();  // Ks/Vs ready

        // QK^T swapped: sacc[nt][r] = S[m=ln][l = nt*16 + quad*4 + r]
        floatx4 sacc[4] = {};
#pragma unroll
        for (int dt = 0; dt < 4; ++dt) {
            half8 kf[4];
#pragma unroll
            for (int nt = 0; nt < 4; ++nt)
                kf[nt] = *(half8*)&Ks[(nt * 16 + ln) * 128 + ((dt * 32 + quad * 8) ^ psw)];
#pragma unroll
            for (int nt = 0; nt < 4; ++nt)
                sacc[nt] = __builtin_amdgcn_mfma_f32_16x16x32_f16(kf[nt], qf[dt], sacc[nt], 0, 0, 0);
        }

        // online softmax; column m=ln is lane-local
        {
            float mx = sacc[0][0];
#pragma unroll
            for (int nt = 0; nt < 4; ++nt)
#pragma unroll
                for (int r = 0; r < 4; ++r) mx = fmaxf(mx, sacc[nt][r]);
            mx = fmaxf(mx, __shfl_xor(mx, 16));
            mx = fmaxf(mx, __shfl_xor(mx, 32));
            if (__ballot(mx > mrow)) {  // rescale only when max grows
                float mnew = fmaxf(mrow, mx);
                float alpha = __expf(mrow - mnew);
                mrow = mnew;
                lrow *= alpha;
                float ar[4];
#pragma unroll
                for (int r = 0; r < 4; ++r) ar[r] = __shfl(alpha, quad * 4 + r, 16);
#pragma unroll
                for (int nt8 = 0; nt8 < 8; ++nt8)
#pragma unroll
                    for (int r = 0; r < 4; ++r) oacc[nt8][r] *= ar[r];
            }
            float psum = 0.f;
#pragma unroll
            for (int nt = 0; nt < 4; ++nt) {
                half4_t h4;
#pragma unroll
                for (int r = 0; r < 4; ++r) {
                    float p = __expf(sacc[nt][r] - mrow);
                    psum += p;
                    h4[r] = (half_t)p;
                }
                *(half4_t*)&Pw[ln * 64 + ((nt * 16 + quad * 4) ^ psw)] = h4;
            }
            psum += __shfl_xor(psum, 16);
            psum += __shfl_xor(psum, 32);
            lrow += psum;
        }

        // PV: A = P (row=ln -> m), B = V (col=ln -> d)
#pragma unroll
        for (int kt = 0; kt < 2; ++kt) {
            half8 a = *(half8*)&Pw[ln * 64 + ((kt * 32 + quad * 8) ^ psw)];
#pragma unroll
            for (int nt8 = 0; nt8 < 8; ++nt8) {
                half8 b = *(half8*)&Vs[(nt8 * 16 + ln) * 64 + ((kt * 32 + quad * 8) ^ psw)];
                oacc[nt8] = __builtin_amdgcn_mfma_f32_16x16x32_f16(a, b, oacc[nt8], 0, 0, 0);
            }
        }
    }

    half_t* Oc = Opart + ((size_t)(c * H_HEADS + h) * M_TOK) * D_HEAD;
    float* ms = mstat + (size_t)(c * H_HEADS + h) * M_TOK;
    float* ls = lstat + (size_t)(c * H_HEADS + h) * M_TOK;
#pragma unroll
    for (int nt8 = 0; nt8 < 8; ++nt8) {
        int col = nt8 * 16 + ln;
#pragma unroll
        for (int r = 0; r < 4; ++r)
            Oc[(size_t)(m0 + quad * 4 + r) * D_HEAD + col] = (half_t)oacc[nt8][r];
    }
    if (lane < 16) {
        ms[m0 + lane] = mrow;
        ls[m0 + lane] = lrow;
    }
}

// ---------------------------------------------------------------------------
// Kernel 4: combine NCHUNK fp16 partials. One wave per (h,m) row.
// ---------------------------------------------------------------------------
__global__ __launch_bounds__(256) void combine_kernel(const half_t* __restrict__ Opart,
                                                      const float* __restrict__ mstat,
                                                      const float* __restrict__ lstat,
                                                      float* __restrict__ out) {
    int gw = blockIdx.x * 4 + (threadIdx.x >> 6);
    int lane = threadIdx.x & 63;
    int h = gw >> 9, m = gw & 511;
    int d = lane * 2;

    float ms[NCHUNK];
    float mg = -INFINITY;
#pragma unroll
    for (int c = 0; c < NCHUNK; ++c) {
        ms[c] = mstat[((c * H_HEADS + h) << 9) + m];
        mg = fmaxf(mg, ms[c]);
    }
    float denom = 0.f, o0 = 0.f, o1 = 0.f;
#pragma unroll
    for (int c = 0; c < NCHUNK; ++c) {
        float e = __expf(ms[c] - mg);
        denom += lstat[((c * H_HEADS + h) << 9) + m] * e;
        const half_t* Oc = Opart + (((size_t)(c * H_HEADS + h) << 9) + m) * D_HEAD + d;
        half2_t v = *(const half2_t*)Oc;
        o0 += (float)v.x * e;
        o1 += (float)v.y * e;
    }
    float inv = 1.0f / denom;
    float* op = out + (size_t)m * N_DIM + h * D_HEAD + d;
    op[0] = o0 * inv;
    op[1] = o1 * inv;
}

// ---------------------------------------------------------------------------
extern "C" void kernel_launch(void* const* d_in, const int* in_sizes, int n_in,
                              void* d_out, int out_size, void* d_ws, size_t ws_size,
                              hipStream_t stream) {
    const float* X = (const float*)d_in[0];
    const float* W = (const float*)d_in[1];
    const float* cK = (const float*)d_in[2];
    const float* cV = (const float*)d_in[3];
    const int* Pp = (const int*)d_in[4];
    float* out = (float*)d_out;

    char* ws = (char*)d_ws;
    // workspace layout (bytes):
    //   Q16    @ 0           (2,097,152)
    //   K16    @ 2,097,152   (16,777,216)
    //   V16T   @ 18,874,368  (16,777,216)
    //   X16    @ 35,651,584  (2,097,152)
    //   W16T   @ 37,748,736  (25,165,824)  [dead after gemm_fused]
    //   Opart16@ 37,748,736  (16,777,216 = NCHUNK(8)*16*512*128*2) [overlays W16T]
    //   mstat  @ 71,303,168  (262,144 used)
    //   lstat  @ 71,827,456  (262,144 used)
    //   total 72,351,744 (unchanged footprint)
    half_t* Q16 = (half_t*)(ws + 0);
    half_t* K16 = (half_t*)(ws + 2097152);
    half_t* V16T = (half_t*)(ws + 18874368);
    half_t* X16 = (half_t*)(ws + 35651584);
    half_t* W16T = (half_t*)(ws + 37748736);
    half_t* Opart = (half_t*)(ws + 37748736);
    float* mstat = (float*)(ws + 71303168);
    float* lstat = (float*)(ws + 71827456);

    prep_kernel<<<9728, 256, 0, stream>>>(cK, cV, W, X, Pp, K16, V16T, W16T, X16);
    gemm_fused_kernel<<<dim3(48, 8), 256, 0, stream>>>(X16, W16T, Pp, Q16, K16, V16T);
    attn_partial_kernel<<<1024, 256, 0, stream>>>(Q16, K16, V16T, Opart, mstat, lstat);
    combine_kernel<<<2048, 256, 0, stream>>>(Opart, mstat, lstat, out);
}

// Round 4
// 212.400 us; speedup vs baseline: 1.1371x; 1.0455x over previous
//
#include <hip/hip_runtime.h>
#include <math.h>

typedef _Float16 half_t;
typedef _Float16 half8 __attribute__((ext_vector_type(8)));
typedef _Float16 half4_t __attribute__((ext_vector_type(4)));
typedef _Float16 half2_t __attribute__((ext_vector_type(2)));
typedef float floatx4 __attribute__((ext_vector_type(4)));

#define M_TOK 512
#define N_DIM 2048
#define D_HEAD 128
#define H_HEADS 16
#define L_CACHE 4096
#define THREE_N 6144
#define NCHUNK 8
#define LCHUNK 512

// ---------------------------------------------------------------------------
// Kernel 1: prep for GEMM inputs only. Regions by blockIdx.x:
//   [0,3072)     transpose W [K,N3] -> W16T [N3,K] fp16, 64x64 tiles
//   [3072,3584)  convert X fp32 -> X16
// (K/V cache conversion moved into mega_kernel to overlap with GEMM.)
// ---------------------------------------------------------------------------
__global__ __launch_bounds__(256) void prep_kernel(const float* __restrict__ W,
                                                   const float* __restrict__ X,
                                                   half_t* __restrict__ W16T,
                                                   half_t* __restrict__ X16) {
    __shared__ half_t tile[64 * 66];  // transposed tile: [64 out-rows][64+2 pad]
    int b = blockIdx.x;
    int t = threadIdx.x;

    if (b < 3072) {  // transpose W: 64(k) x 64(n) tiles
        int n0 = (b % 96) * 64, k0 = (b / 96) * 64;
        {
            int k = t >> 2, c0 = (t & 3) * 16;
            const float* src = W + (size_t)(k0 + k) * THREE_N + n0 + c0;
            float4 v[4];
#pragma unroll
            for (int j = 0; j < 4; ++j) v[j] = *(const float4*)(src + j * 4);
#pragma unroll
            for (int j = 0; j < 4; ++j) {
                tile[(c0 + j * 4 + 0) * 66 + k] = (half_t)v[j].x;
                tile[(c0 + j * 4 + 1) * 66 + k] = (half_t)v[j].y;
                tile[(c0 + j * 4 + 2) * 66 + k] = (half_t)v[j].z;
                tile[(c0 + j * 4 + 3) * 66 + k] = (half_t)v[j].w;
            }
        }
        __syncthreads();
        {
            int n = t >> 2, kg = (t & 3) * 16;
            half_t* dst = W16T + (size_t)(n0 + n) * N_DIM + k0 + kg;
            *(half8*)(dst) = *(half8*)&tile[n * 66 + kg];
            *(half8*)(dst + 8) = *(half8*)&tile[n * 66 + kg + 8];
        }
        return;
    }
    b -= 3072;
    {  // convert X: 2048 elems/block
        size_t i = (size_t)b * 2048 + t * 4;
        float4 v0 = *(const float4*)(X + i);
        float4 v1 = *(const float4*)(X + i + 1024);
        half4_t h0 = {(half_t)v0.x, (half_t)v0.y, (half_t)v0.z, (half_t)v0.w};
        half4_t h1 = {(half_t)v1.x, (half_t)v1.y, (half_t)v1.z, (half_t)v1.w};
        *(half4_t*)(X16 + i) = h0;
        *(half4_t*)(X16 + i + 1024) = h1;
    }
}

// ---------------------------------------------------------------------------
// Kernel 2 (mega): GEMM blocks + K/V cache-conversion blocks co-dispatched.
//   b in [0,384):      fused GEMM + RMS-norm + scatter (as before).
//                      bx=b%48 (0..15 q, 16..31 k, 32..47 v), by=b/48.
//   b in [384,4480):   convert cache_K fp32 -> K16 fp16 (skip rows [P,P+M)).
//   b in [4480,6528):  transpose cache_V -> V16T fp16 64x64 (skip [P,P+M)).
// Converter writes are row-disjoint from GEMM's K16/V16T writes -> no order
// dependency. Converter blocks backfill CU slots & HBM BW idle during GEMM.
// LDS is a union (46.6KB) so GEMM keeps 3 blocks/CU.
// ---------------------------------------------------------------------------
__global__ __launch_bounds__(256) void mega_kernel(const half_t* __restrict__ X16,
                                                   const half_t* __restrict__ W16T,
                                                   const float* __restrict__ cK,
                                                   const float* __restrict__ cV,
                                                   const int* __restrict__ Pp,
                                                   half_t* __restrict__ Q16,
                                                   half_t* __restrict__ K16,
                                                   half_t* __restrict__ V16T) {
    __shared__ __align__(16) char smem[46592];
    const int t = threadIdx.x;
    int b = blockIdx.x;

    if (b >= 384) {
        b -= 384;
        const int P = *Pp;
        if (b < 4096) {  // convert K: 2048 elems = 16 l-rows of one head
            int l0 = (b & 255) * 16;
            if (l0 >= P && l0 + 16 <= P + M_TOK) return;  // fully overwritten by gemm
            size_t i = (size_t)b * 2048 + t * 4;
            int r0 = l0 + (t >> 5), r1 = r0 + 8;  // cache rows of the two float4s
            float4 v0 = *(const float4*)(cK + i);
            float4 v1 = *(const float4*)(cK + i + 1024);
            half4_t h0 = {(half_t)v0.x, (half_t)v0.y, (half_t)v0.z, (half_t)v0.w};
            half4_t h1 = {(half_t)v1.x, (half_t)v1.y, (half_t)v1.z, (half_t)v1.w};
            if (r0 < P || r0 >= P + M_TOK) *(half4_t*)(K16 + i) = h0;
            if (r1 < P || r1 >= P + M_TOK) *(half4_t*)(K16 + i + 1024) = h1;
            return;
        }
        b -= 4096;
        {  // transpose V: 64(l) x 64(d) tiles, 128 tiles/head
            int h = b >> 7;
            int rem = b & 127;
            int lt = rem >> 1, dt = rem & 1;
            int l0 = lt * 64, d0 = dt * 64;
            if (l0 >= P && l0 + 64 <= P + M_TOK) return;  // fully overwritten
            bool overlap = (l0 < P + M_TOK) && (l0 + 64 > P);
            half_t* tile = (half_t*)smem;  // [64][66]
            {
                int l = t >> 2, c0 = (t & 3) * 16;
                const float* src = cV + ((size_t)h * L_CACHE + l0 + l) * D_HEAD + d0 + c0;
                float4 v[4];
#pragma unroll
                for (int j = 0; j < 4; ++j) v[j] = *(const float4*)(src + j * 4);
#pragma unroll
                for (int j = 0; j < 4; ++j) {
                    tile[(c0 + j * 4 + 0) * 66 + l] = (half_t)v[j].x;
                    tile[(c0 + j * 4 + 1) * 66 + l] = (half_t)v[j].y;
                    tile[(c0 + j * 4 + 2) * 66 + l] = (half_t)v[j].z;
                    tile[(c0 + j * 4 + 3) * 66 + l] = (half_t)v[j].w;
                }
            }
            __syncthreads();
            {
                int d = t >> 2, lg = (t & 3) * 16;
                half_t* dst = V16T + ((size_t)h * D_HEAD + d0 + d) * L_CACHE + l0 + lg;
                if (!overlap) {
                    *(half8*)(dst) = *(half8*)&tile[d * 66 + lg];
                    *(half8*)(dst + 8) = *(half8*)&tile[d * 66 + lg + 8];
                } else {  // straddling [P,P+M): per-element guard (rare path)
#pragma unroll
                    for (int j = 0; j < 16; ++j) {
                        int l = l0 + lg + j;
                        if (l < P || l >= P + M_TOK) dst[j] = tile[d * 66 + lg + j];
                    }
                }
            }
            return;
        }
    }

    // ----- GEMM path (b in [0,384)) -----
    half_t* As = (half_t*)smem;                  // [64][72]
    half_t* Bs = (half_t*)(smem + 9216);         // [128][72]
    half_t* Vt = (half_t*)(smem + 27648);        // [128][72]
    float* ssb = (float*)(smem + 46080);         // [4][32]
    const int wid = t >> 6, lane = t & 63;
    const int quad = lane >> 4, ln = lane & 15;
    const int bx = b % 48, by = b / 48;
    const int m0 = by * 64, n0 = bx * 128;
    const int wm = (wid >> 1) * 32, wn = (wid & 1) * 64;

    floatx4 acc[2][4] = {};

    const int ar = t >> 3, ag = (t & 7) * 8;  // A: 32 rows/pass, 2 passes
    const int br = t >> 3, bg = (t & 7) * 8;  // B: 32 rows/pass, 4 passes

    for (int k0 = 0; k0 < N_DIM; k0 += 64) {
        __syncthreads();
#pragma unroll
        for (int p = 0; p < 2; ++p) {
            int r = ar + p * 32;
            *(half8*)&As[r * 72 + ag] =
                *(const half8*)(X16 + (size_t)(m0 + r) * N_DIM + k0 + ag);
        }
#pragma unroll
        for (int p = 0; p < 4; ++p) {
            int r = br + p * 32;
            *(half8*)&Bs[r * 72 + bg] =
                *(const half8*)(W16T + (size_t)(n0 + r) * N_DIM + k0 + bg);
        }
        __syncthreads();
#pragma unroll
        for (int kt = 0; kt < 2; ++kt) {
            half8 a[2], bb[4];
#pragma unroll
            for (int i = 0; i < 2; ++i)
                a[i] = *(half8*)&As[(wm + i * 16 + ln) * 72 + kt * 32 + quad * 8];
#pragma unroll
            for (int j = 0; j < 4; ++j)
                bb[j] = *(half8*)&Bs[(wn + j * 16 + ln) * 72 + kt * 32 + quad * 8];
#pragma unroll
            for (int i = 0; i < 2; ++i)
#pragma unroll
                for (int j = 0; j < 4; ++j)
                    acc[i][j] = __builtin_amdgcn_mfma_f32_16x16x32_f16(a[i], bb[j], acc[i][j], 0, 0, 0);
        }
    }

    const int seg = bx >> 4, h = bx & 15;
    const int P = *Pp;

    if (seg < 2) {  // q or k: RMS-norm then write
        float ss[2][4], scale[2][4];
#pragma unroll
        for (int i = 0; i < 2; ++i)
#pragma unroll
            for (int r = 0; r < 4; ++r) {
                float s = 0.f;
#pragma unroll
                for (int j = 0; j < 4; ++j) s += acc[i][j][r] * acc[i][j][r];
#pragma unroll
                for (int msk = 1; msk < 16; msk <<= 1) s += __shfl_xor(s, msk, 64);
                ss[i][r] = s;
            }
        if (ln == 0) {
#pragma unroll
            for (int i = 0; i < 2; ++i)
#pragma unroll
                for (int r = 0; r < 4; ++r)
                    ssb[wid * 32 + i * 16 + quad * 4 + r] = ss[i][r];
        }
        __syncthreads();
#pragma unroll
        for (int i = 0; i < 2; ++i)
#pragma unroll
            for (int r = 0; r < 4; ++r)
                scale[i][r] =
                    rsqrtf((ss[i][r] + ssb[(wid ^ 1) * 32 + i * 16 + quad * 4 + r]) * (1.0f / 128.0f));
#pragma unroll
        for (int i = 0; i < 2; ++i) {
            int mbase = m0 + wm + i * 16 + quad * 4;
#pragma unroll
            for (int j = 0; j < 4; ++j) {
                int col = wn + j * 16 + ln;
#pragma unroll
                for (int r = 0; r < 4; ++r) {
                    int m = mbase + r;
                    half_t val = (half_t)(acc[i][j][r] * scale[i][r]);
                    if (seg == 0)
                        Q16[((size_t)h * M_TOK + m) * D_HEAD + col] = val;
                    else
                        K16[((size_t)h * L_CACHE + P + m) * D_HEAD + col] = val;
                }
            }
        }
    } else {  // v: transpose via LDS, write V^T columns (coalesced 16B stores)
#pragma unroll
        for (int i = 0; i < 2; ++i) {
            int mbase = wm + i * 16 + quad * 4;
#pragma unroll
            for (int j = 0; j < 4; ++j) {
                int d = wn + j * 16 + ln;
#pragma unroll
                for (int r = 0; r < 4; ++r)
                    Vt[d * 72 + mbase + r] = (half_t)acc[i][j][r];
            }
        }
        __syncthreads();
#pragma unroll
        for (int p = 0; p < 4; ++p) {
            int s = p * 256 + t;
            int d = s >> 3, sg = s & 7;
            *(half8*)(V16T + ((size_t)h * D_HEAD + d) * L_CACHE + P + m0 + sg * 8) =
                *(half8*)&Vt[d * 72 + sg * 8];
        }
    }
}

// ---------------------------------------------------------------------------
// Kernel 3: flash attention partial over L-chunk of 512. grid = 1024 blocks
// (8 m-blocks x 16 h x 8 c), all co-resident (4 blocks/CU, 40KB LDS).
// 64 m-rows per block: 4 waves x 1 strip of 16 rows. Swapped QK^T, XOR-
// swizzled LDS (T2: col ^= (row&7)<<3, power-of-2 pitches) for conflict-free
// ds_read_b128. XCD decode: chunk c -> XCD c, K/V working set = 4MB = L2.
// ---------------------------------------------------------------------------
__global__ __launch_bounds__(256, 4) void attn_partial_kernel(const half_t* __restrict__ Q16,
                                                              const half_t* __restrict__ K16,
                                                              const half_t* __restrict__ V16T,
                                                              half_t* __restrict__ Opart,
                                                              float* __restrict__ mstat,
                                                              float* __restrict__ lstat) {
    __shared__ half_t Ks[64 * 128];      // [l][d], swizzled
    __shared__ half_t Vs[128 * 64];      // [d][l], swizzled
    __shared__ half_t Ps[4 * 16 * 64];   // per-wave P[m][l], swizzled
    const int t = threadIdx.x, w = t >> 6, lane = t & 63;
    const int quad = lane >> 4, ln = lane & 15;

    // bijective XCD decode over 1024 = 128 slots x 8 XCDs
    const int bid = blockIdx.x;
    const int xcd = bid & 7, slot = bid >> 3;
    const int pair = (xcd << 4) | (slot >> 3);  // 16 (h,c) pairs per XCD
    const int h = pair & 15, c = pair >> 4, mi = slot & 7;
    const int mb = mi * 64;

    const half_t* Qh = Q16 + (size_t)h * M_TOK * D_HEAD;
    const half_t* Kh = K16 + (size_t)h * L_CACHE * D_HEAD;
    const half_t* Vh = V16T + (size_t)h * D_HEAD * L_CACHE;

    // Q fragments (B-operand of swapped mfma): col=ln -> m, k=quad*8+i -> d
    const int m0 = mb + w * 16;
    half8 qf[4];
#pragma unroll
    for (int dt = 0; dt < 4; ++dt)
        qf[dt] = *(const half8*)(Qh + (size_t)(m0 + ln) * D_HEAD + dt * 32 + quad * 8);

    floatx4 oacc[8] = {};
    float mrow = -INFINITY;
    float lrow = 0.f;

    half_t* Pw = Ps + w * (16 * 64);
    const int psw = (ln & 7) << 3;  // P swizzle key (row = ln)

    const int l0base = c * LCHUNK;
    const int kr = t >> 4, kc = (t & 15) * 8;  // K staging: 16 rows/pass x 4
    const int vr = t >> 3, vc = (t & 7) * 8;   // V staging: 32 rows/pass x 4
    const int ksw = (kr & 7) << 3;             // K stage swizzle (row&7 = kr&7)
    const int vsw = (vr & 7) << 3;             // V stage swizzle (row&7 = vr&7)

    // prologue: load tile 0 into regs
    half8 kreg[4], vreg[4];
#pragma unroll
    for (int p = 0; p < 4; ++p) {
        kreg[p] = *(const half8*)(Kh + (size_t)(l0base + p * 16 + kr) * D_HEAD + kc);
        vreg[p] = *(const half8*)(Vh + (size_t)(p * 32 + vr) * L_CACHE + l0base + vc);
    }

    for (int it = 0; it < LCHUNK / 64; ++it) {
        __syncthreads();  // previous compute done reading Ks/Vs
#pragma unroll
        for (int p = 0; p < 4; ++p)
            *(half8*)&Ks[(p * 16 + kr) * 128 + (kc ^ ksw)] = kreg[p];
#pragma unroll
        for (int p = 0; p < 4; ++p)
            *(half8*)&Vs[(p * 32 + vr) * 64 + (vc ^ vsw)] = vreg[p];
        if (it + 1 < LCHUNK / 64) {  // prefetch next tile under compute
            int l1 = l0base + (it + 1) * 64;
#pragma unroll
            for (int p = 0; p < 4; ++p) {
                kreg[p] = *(const half8*)(Kh + (size_t)(l1 + p * 16 + kr) * D_HEAD + kc);
                vreg[p] = *(const half8*)(Vh + (size_t)(p * 32 + vr) * L_CACHE + l1 + vc);
            }
        }
        __syncthreads();  // Ks/Vs ready

        // QK^T swapped: sacc[nt][r] = S[m=ln][l = nt*16 + quad*4 + r]
        floatx4 sacc[4] = {};
#pragma unroll
        for (int dt = 0; dt < 4; ++dt) {
            half8 kf[4];
#pragma unroll
            for (int nt = 0; nt < 4; ++nt)
                kf[nt] = *(half8*)&Ks[(nt * 16 + ln) * 128 + ((dt * 32 + quad * 8) ^ psw)];
#pragma unroll
            for (int nt = 0; nt < 4; ++nt)
                sacc[nt] = __builtin_amdgcn_mfma_f32_16x16x32_f16(kf[nt], qf[dt], sacc[nt], 0, 0, 0);
        }

        // online softmax; column m=ln is lane-local
        {
            float mx = sacc[0][0];
#pragma unroll
            for (int nt = 0; nt < 4; ++nt)
#pragma unroll
                for (int r = 0; r < 4; ++r) mx = fmaxf(mx, sacc[nt][r]);
            mx = fmaxf(mx, __shfl_xor(mx, 16));
            mx = fmaxf(mx, __shfl_xor(mx, 32));
            if (__ballot(mx > mrow)) {  // rescale only when max grows
                float mnew = fmaxf(mrow, mx);
                float alpha = __expf(mrow - mnew);
                mrow = mnew;
                lrow *= alpha;
                float ar[4];
#pragma unroll
                for (int r = 0; r < 4; ++r) ar[r] = __shfl(alpha, quad * 4 + r, 16);
#pragma unroll
                for (int nt8 = 0; nt8 < 8; ++nt8)
#pragma unroll
                    for (int r = 0; r < 4; ++r) oacc[nt8][r] *= ar[r];
            }
            float psum = 0.f;
#pragma unroll
            for (int nt = 0; nt < 4; ++nt) {
                half4_t h4;
#pragma unroll
                for (int r = 0; r < 4; ++r) {
                    float p = __expf(sacc[nt][r] - mrow);
                    psum += p;
                    h4[r] = (half_t)p;
                }
                *(half4_t*)&Pw[ln * 64 + ((nt * 16 + quad * 4) ^ psw)] = h4;
            }
            psum += __shfl_xor(psum, 16);
            psum += __shfl_xor(psum, 32);
            lrow += psum;
        }

        // PV: A = P (row=ln -> m), B = V (col=ln -> d)
#pragma unroll
        for (int kt = 0; kt < 2; ++kt) {
            half8 a = *(half8*)&Pw[ln * 64 + ((kt * 32 + quad * 8) ^ psw)];
#pragma unroll
            for (int nt8 = 0; nt8 < 8; ++nt8) {
                half8 b = *(half8*)&Vs[(nt8 * 16 + ln) * 64 + ((kt * 32 + quad * 8) ^ psw)];
                oacc[nt8] = __builtin_amdgcn_mfma_f32_16x16x32_f16(a, b, oacc[nt8], 0, 0, 0);
            }
        }
    }

    half_t* Oc = Opart + ((size_t)(c * H_HEADS + h) * M_TOK) * D_HEAD;
    float* ms = mstat + (size_t)(c * H_HEADS + h) * M_TOK;
    float* ls = lstat + (size_t)(c * H_HEADS + h) * M_TOK;
#pragma unroll
    for (int nt8 = 0; nt8 < 8; ++nt8) {
        int col = nt8 * 16 + ln;
#pragma unroll
        for (int r = 0; r < 4; ++r)
            Oc[(size_t)(m0 + quad * 4 + r) * D_HEAD + col] = (half_t)oacc[nt8][r];
    }
    if (lane < 16) {
        ms[m0 + lane] = mrow;
        ls[m0 + lane] = lrow;
    }
}

// ---------------------------------------------------------------------------
// Kernel 4: combine NCHUNK fp16 partials. One wave per (h,m) row.
// ---------------------------------------------------------------------------
__global__ __launch_bounds__(256) void combine_kernel(const half_t* __restrict__ Opart,
                                                      const float* __restrict__ mstat,
                                                      const float* __restrict__ lstat,
                                                      float* __restrict__ out) {
    int gw = blockIdx.x * 4 + (threadIdx.x >> 6);
    int lane = threadIdx.x & 63;
    int h = gw >> 9, m = gw & 511;
    int d = lane * 2;

    float ms[NCHUNK];
    float mg = -INFINITY;
#pragma unroll
    for (int c = 0; c < NCHUNK; ++c) {
        ms[c] = mstat[((c * H_HEADS + h) << 9) + m];
        mg = fmaxf(mg, ms[c]);
    }
    float denom = 0.f, o0 = 0.f, o1 = 0.f;
#pragma unroll
    for (int c = 0; c < NCHUNK; ++c) {
        float e = __expf(ms[c] - mg);
        denom += lstat[((c * H_HEADS + h) << 9) + m] * e;
        const half_t* Oc = Opart + (((size_t)(c * H_HEADS + h) << 9) + m) * D_HEAD + d;
        half2_t v = *(const half2_t*)Oc;
        o0 += (float)v.x * e;
        o1 += (float)v.y * e;
    }
    float inv = 1.0f / denom;
    float* op = out + (size_t)m * N_DIM + h * D_HEAD + d;
    op[0] = o0 * inv;
    op[1] = o1 * inv;
}

// ---------------------------------------------------------------------------
extern "C" void kernel_launch(void* const* d_in, const int* in_sizes, int n_in,
                              void* d_out, int out_size, void* d_ws, size_t ws_size,
                              hipStream_t stream) {
    const float* X = (const float*)d_in[0];
    const float* W = (const float*)d_in[1];
    const float* cK = (const float*)d_in[2];
    const float* cV = (const float*)d_in[3];
    const int* Pp = (const int*)d_in[4];
    float* out = (float*)d_out;

    char* ws = (char*)d_ws;
    // workspace layout (bytes):
    //   Q16    @ 0           (2,097,152)
    //   K16    @ 2,097,152   (16,777,216)
    //   V16T   @ 18,874,368  (16,777,216)
    //   X16    @ 35,651,584  (2,097,152)
    //   W16T   @ 37,748,736  (25,165,824)  [dead after mega]
    //   Opart16@ 37,748,736  (16,777,216 = NCHUNK(8)*16*512*128*2) [overlays W16T]
    //   mstat  @ 71,303,168  (262,144 used)
    //   lstat  @ 71,827,456  (262,144 used)
    //   total 72,351,744 (unchanged footprint)
    half_t* Q16 = (half_t*)(ws + 0);
    half_t* K16 = (half_t*)(ws + 2097152);
    half_t* V16T = (half_t*)(ws + 18874368);
    half_t* X16 = (half_t*)(ws + 35651584);
    half_t* W16T = (half_t*)(ws + 37748736);
    half_t* Opart = (half_t*)(ws + 37748736);
    float* mstat = (float*)(ws + 71303168);
    float* lstat = (float*)(ws + 71827456);

    prep_kernel<<<3584, 256, 0, stream>>>(W, X, W16T, X16);
    mega_kernel<<<6528, 256, 0, stream>>>(X16, W16T, cK, cV, Pp, Q16, K16, V16T);
    attn_partial_kernel<<<1024, 256, 0, stream>>>(Q16, K16, V16T, Opart, mstat, lstat);
    combine_kernel<<<2048, 256, 0, stream>>>(Opart, mstat, lstat, out);
}